// Round 5
// baseline (1926.929 us; speedup 1.0000x reference)
//
#include <hip/hip_runtime.h>

#define DIM 128

// f32 -> bf16 bits (RNE) and unpack helpers
static __device__ __forceinline__ unsigned f2bf_bits(float f) {
  unsigned u = __float_as_uint(f);
  return (u + 0x7fffu + ((u >> 16) & 1u)) >> 16;
}
static __device__ __forceinline__ unsigned packbf(float a, float b) {
  return (f2bf_bits(a) & 0xffffu) | (f2bf_bits(b) << 16);
}
static __device__ __forceinline__ float bfu_lo(unsigned pk) { return __uint_as_float(pk << 16); }
static __device__ __forceinline__ float bfu_hi(unsigned pk) { return __uint_as_float(pk & 0xffff0000u); }

// adaptive edge-index element read: fl64 ? int64 storage (lo word) : int32
static __device__ __forceinline__ int eread(const int* __restrict__ e, long long idx, int fl64) {
  return fl64 ? e[idx * 2] : e[idx];
}

// ---- probe index dtype: int64 => odd 32-bit words are all zero ----
__global__ void k_probe(const int* __restrict__ eidx, int* __restrict__ iflag) {
  int lane = threadIdx.x;  // 64
  int w = eidx[lane * 2 + 1];
  unsigned long long m = __ballot(w == 0);
  if (lane == 0) *iflag = (__popcll(m) >= 48) ? 1 : 0;
}

// ---- degree histogram over dst ----
__global__ __launch_bounds__(256) void k_deg(const int* __restrict__ eidx, int E,
                                             const int* __restrict__ iflag,
                                             int* __restrict__ deg) {
  int e = blockIdx.x * 256 + threadIdx.x;
  if (e >= E) return;
  int fl = *iflag;
  int d = eread(eidx, (long long)E + e, fl);
  atomicAdd(&deg[d], 1);
}

// ---- dinv = rsqrt(deg + 1) ----
__global__ __launch_bounds__(256) void k_dinv(const int* __restrict__ deg,
                                              float* __restrict__ dinv, int n) {
  int i = blockIdx.x * 256 + threadIdx.x;
  if (i < n) dinv[i] = rsqrtf((float)(deg[i] + 1));
}

// ---- exclusive scan of deg -> off (single block) ----
__global__ void k_scan(const int* __restrict__ deg, int* __restrict__ off, int n, int E) {
  __shared__ int sums[256];
  int t = threadIdx.x;
  int chunk = (n + 255) / 256;
  int lo = t * chunk, hi = lo + chunk < n ? lo + chunk : n;
  int s = 0;
  for (int i = lo; i < hi; ++i) s += deg[i];
  sums[t] = s;
  __syncthreads();
  if (t == 0) {
    int run = 0;
    for (int i = 0; i < 256; ++i) { int v = sums[i]; sums[i] = run; run += v; }
  }
  __syncthreads();
  int run = sums[t];
  for (int i = lo; i < hi; ++i) { off[i] = run; run += deg[i]; }
  if (t == 0) off[n] = E;
}

// ---- cursors = copy of offsets ----
__global__ __launch_bounds__(256) void k_cur(const int* __restrict__ off,
                                             int* __restrict__ cur, int n) {
  int i = blockIdx.x * 256 + threadIdx.x;
  if (i < n) cur[i] = off[i];
}

// ---- counting-sort edges by dst: ssrc[slot] = src ----
__global__ __launch_bounds__(256) void k_sort(const int* __restrict__ eidx, int E,
                                              const int* __restrict__ iflag,
                                              int* __restrict__ cur,
                                              int* __restrict__ ssrc) {
  int e = blockIdx.x * 256 + threadIdx.x;
  if (e >= E) return;
  int fl = *iflag;
  int s = eread(eidx, e, fl);
  int d = eread(eidx, (long long)E + e, fl);
  int pos = atomicAdd(&cur[d], 1);
  ssrc[pos] = s;
}

// ---- fused: CSR gather-aggregate (fp32) -> LDS bf16 tile -> GEMM -> preb (ws) + BN partials ----
// block = 256 thr (4 waves), 64 dst rows. LDS: As2 64x68 uints (17KB) + Wb2 128x64 uints (32KB).
__global__ __launch_bounds__(256) void k_aggemm(
    const float* __restrict__ x, const int* __restrict__ ssrc,
    const int* __restrict__ off, const int* __restrict__ deg,
    const float* __restrict__ dinv, const float* __restrict__ W,
    const float* __restrict__ bias, unsigned* __restrict__ preb,
    float* __restrict__ bnsum, float* __restrict__ bnsq, int n) {
  __shared__ unsigned As2[64 * 68];    // row-major, k-pairs, stride 68
  __shared__ unsigned Wb2[DIM * 64];   // Wb2[k*64 + c2] = pack(W[k][2c2], W[k][2c2+1])
  int tid = threadIdx.x;
  int base = blockIdx.x * 64;

  // stage W as packed bf16
#pragma unroll
  for (int it = 0; it < 32; ++it) {
    int j = it * 256 + tid;            // j = k*64 + c2
    float2 v = ((const float2*)W)[j];
    Wb2[j] = packbf(v.x, v.y);
  }

  // aggregate: wave wv handles local rows wv*16 .. wv*16+15
  int lane = tid & 63;
  int wv = tid >> 6;
  for (int j = 0; j < 16; ++j) {
    int rl = wv * 16 + j;
    int g = base + rl;
    float ax = 0.f, ay = 0.f;
    if (g < n) {
      float di = dinv[g];
      float2 xv = *(const float2*)(x + (size_t)g * DIM + lane * 2);
      ax = xv.x * di * di;
      ay = xv.y * di * di;
      int e0 = off[g], e1 = e0 + deg[g];
      for (int e = e0; e < e1; ++e) {
        int s = ssrc[e];
        float w = dinv[s] * di;
        float2 sv = *(const float2*)(x + (size_t)s * DIM + lane * 2);
        ax = fmaf(w, sv.x, ax);
        ay = fmaf(w, sv.y, ay);
      }
    }
    As2[rl * 68 + lane] = packbf(ax, ay);  // lane = k-pair index
  }
  __syncthreads();

  // GEMM: thread = (cg, rg): 4 rows (rg*4..+3) x 8 cols (cg*8..+7)
  int cg = tid & 15, rg = tid >> 4;
  float acc[4][8];
#pragma unroll
  for (int r = 0; r < 4; ++r)
#pragma unroll
    for (int u = 0; u < 8; ++u) acc[r][u] = 0.f;

  for (int kt = 0; kt < 32; ++kt) {   // k-quad kt*4 .. +3
    uint2 aq[4];
#pragma unroll
    for (int r = 0; r < 4; ++r)
      aq[r] = *(const uint2*)&As2[(rg * 4 + r) * 68 + kt * 2];
    float af[4][4];
#pragma unroll
    for (int r = 0; r < 4; ++r) {
      af[r][0] = bfu_lo(aq[r].x); af[r][1] = bfu_hi(aq[r].x);
      af[r][2] = bfu_lo(aq[r].y); af[r][3] = bfu_hi(aq[r].y);
    }
#pragma unroll
    for (int j = 0; j < 4; ++j) {
      int k = kt * 4 + j;
      uint4 wq = *(const uint4*)&Wb2[k * 64 + cg * 4];
      float wf[8] = {bfu_lo(wq.x), bfu_hi(wq.x), bfu_lo(wq.y), bfu_hi(wq.y),
                     bfu_lo(wq.z), bfu_hi(wq.z), bfu_lo(wq.w), bfu_hi(wq.w)};
#pragma unroll
      for (int r = 0; r < 4; ++r)
#pragma unroll
        for (int u = 0; u < 8; ++u)
          acc[r][u] = fmaf(af[r][j], wf[u], acc[r][u]);
    }
  }

  // epilogue: +bias, bf16 store to ws scratch, BN partials
  float bs[8];
#pragma unroll
  for (int u = 0; u < 8; ++u) bs[u] = bias[cg * 8 + u];
  float cs[8], cq[8];
#pragma unroll
  for (int u = 0; u < 8; ++u) { cs[u] = 0.f; cq[u] = 0.f; }

#pragma unroll
  for (int r = 0; r < 4; ++r) {
    int g = base + rg * 4 + r;
    if (g < n) {
      float v[8];
#pragma unroll
      for (int u = 0; u < 8; ++u) {
        v[u] = acc[r][u] + bs[u];
        cs[u] += v[u];
        cq[u] += v[u] * v[u];
      }
      unsigned* op = preb + (size_t)g * 64 + cg * 4;
#pragma unroll
      for (int w = 0; w < 4; ++w) op[w] = packbf(v[2 * w], v[2 * w + 1]);
    }
  }

#pragma unroll
  for (int u = 0; u < 8; ++u) {
    cs[u] += __shfl_xor(cs[u], 16); cs[u] += __shfl_xor(cs[u], 32);
    cq[u] += __shfl_xor(cq[u], 16); cq[u] += __shfl_xor(cq[u], 32);
  }
  if ((tid & 63) < 16) {
#pragma unroll
    for (int u = 0; u < 8; ++u) {
      unsafeAtomicAdd(&bnsum[cg * 8 + u], cs[u]);
      unsafeAtomicAdd(&bnsq[cg * 8 + u],  cq[u]);
    }
  }
}

// ---- BN finalize ----
__global__ void k_bn(const float* __restrict__ bnsum, const float* __restrict__ bnsq,
                     const float* __restrict__ gma, const float* __restrict__ bta,
                     float* __restrict__ sc, float* __restrict__ sh, float invn) {
  int c = threadIdx.x;
  float mean = bnsum[c] * invn;
  float var = bnsq[c] * invn - mean * mean;
  float inv = rsqrtf(var + 1e-5f);
  float g = gma[c] * inv;
  sc[c] = g;
  sh[c] = bta[c] - mean * g;
}

// ---- affine + PReLU + residual -> FP32 output ----
__global__ __launch_bounds__(256) void k_final(const unsigned* __restrict__ preb,
                                               const float* __restrict__ x,
                                               const float* __restrict__ sc,
                                               const float* __restrict__ sh,
                                               const float* __restrict__ apre,
                                               float* __restrict__ out, int n) {
  int t = blockIdx.x * 256 + threadIdx.x;
  int i = t >> 6, p = t & 63;
  if (i >= n) return;
  float a = apre[0];
  int c = p * 2;
  unsigned pk = preb[(size_t)i * 64 + p];
  float t0 = bfu_lo(pk) * sc[c] + sh[c];
  float t1 = bfu_hi(pk) * sc[c + 1] + sh[c + 1];
  t0 = t0 > 0.f ? t0 : a * t0;
  t1 = t1 > 0.f ? t1 : a * t1;
  float2 xv = *(const float2*)(x + (size_t)i * DIM + c);
  t0 += xv.x;
  t1 += xv.y;
  *(float2*)(out + (size_t)i * DIM + c) = make_float2(t0, t1);
}

extern "C" void kernel_launch(void* const* d_in, const int* in_sizes, int n_in,
                              void* d_out, int out_size, void* d_ws, size_t ws_size,
                              hipStream_t stream) {
  (void)n_in; (void)out_size; (void)ws_size;
  const float* x    = (const float*)d_in[0];
  const float* W    = (const float*)d_in[1];
  const float* b    = (const float*)d_in[2];
  const float* gma  = (const float*)d_in[3];
  const float* bta  = (const float*)d_in[4];
  const float* apre = (const float*)d_in[5];
  const int* eidx   = (const int*)d_in[6];
  float* out        = (float*)d_out;   // fp32 output per reference dtype

  const int N = in_sizes[0] / DIM;
  const int E = in_sizes[6] / 2;

  char* wsb = (char*)d_ws;
  size_t off_b = 0;
  auto take = [&](size_t bytes) -> void* {
    void* p = wsb + off_b;
    off_b += (bytes + 255) & ~(size_t)255;
    return p;
  };
  int*      iflag = (int*)     take(256);
  int*      deg   = (int*)     take((size_t)N * 4);
  int*      offs  = (int*)     take((size_t)(N + 1) * 4);
  int*      cur   = (int*)     take((size_t)N * 4);
  float*    dinv  = (float*)   take((size_t)N * 4);
  int*      ssrc  = (int*)     take((size_t)E * 4);
  unsigned* preb  = (unsigned*)take((size_t)N * 64 * 4);  // pre-BN, packed bf16 pairs
  float*    bnsum = (float*)   take(DIM * 4);
  float*    bnsq  = (float*)   take(DIM * 4);
  float*    sc    = (float*)   take(DIM * 4);
  float*    sh    = (float*)   take(DIM * 4);
  // total ~34 MB

  hipMemsetAsync(deg, 0, (size_t)N * 4, stream);
  hipMemsetAsync(bnsum, 0, DIM * 4, stream);
  hipMemsetAsync(bnsq, 0, DIM * 4, stream);

  k_probe <<<1, 64, 0, stream>>>(eidx, iflag);
  k_deg   <<<(E + 255) / 256, 256, 0, stream>>>(eidx, E, iflag, deg);
  k_dinv  <<<(N + 255) / 256, 256, 0, stream>>>(deg, dinv, N);
  k_scan  <<<1, 256, 0, stream>>>(deg, offs, N, E);
  k_cur   <<<(N + 255) / 256, 256, 0, stream>>>(offs, cur, N);
  k_sort  <<<(E + 255) / 256, 256, 0, stream>>>(eidx, E, iflag, cur, ssrc);
  k_aggemm<<<(N + 63) / 64, 256, 0, stream>>>(x, ssrc, offs, deg, dinv, W, b,
                                              preb, bnsum, bnsq, N);
  k_bn    <<<1, DIM, 0, stream>>>(bnsum, bnsq, gma, bta, sc, sh, 1.0f / (float)N);
  k_final <<<(N * 64 + 255) / 256, 256, 0, stream>>>(preb, x, sc, sh, apre, out, N);
}

// Round 6
// 1866.728 us; speedup vs baseline: 1.0322x; 1.0322x over previous
//
#include <hip/hip_runtime.h>

#define DIM 128

// f32 -> bf16 bits (RNE) and unpack helpers
static __device__ __forceinline__ unsigned f2bf_bits(float f) {
  unsigned u = __float_as_uint(f);
  return (u + 0x7fffu + ((u >> 16) & 1u)) >> 16;
}
static __device__ __forceinline__ unsigned packbf(float a, float b) {
  return (f2bf_bits(a) & 0xffffu) | (f2bf_bits(b) << 16);
}
static __device__ __forceinline__ float bfu_lo(unsigned pk) { return __uint_as_float(pk << 16); }
static __device__ __forceinline__ float bfu_hi(unsigned pk) { return __uint_as_float(pk & 0xffff0000u); }

// adaptive edge-index element read: fl64 ? int64 storage (lo word) : int32
static __device__ __forceinline__ int eread(const int* __restrict__ e, long long idx, int fl64) {
  return fl64 ? e[idx * 2] : e[idx];
}

// ---- probe index dtype: int64 => odd 32-bit words are all zero ----
__global__ void k_probe(const int* __restrict__ eidx, int* __restrict__ iflag) {
  int lane = threadIdx.x;  // 64
  int w = eidx[lane * 2 + 1];
  unsigned long long m = __ballot(w == 0);
  if (lane == 0) *iflag = (__popcll(m) >= 48) ? 1 : 0;
}

// ---- degree histogram over dst ----
__global__ __launch_bounds__(256) void k_deg(const int* __restrict__ eidx, int E,
                                             const int* __restrict__ iflag,
                                             int* __restrict__ deg) {
  int e = blockIdx.x * 256 + threadIdx.x;
  if (e >= E) return;
  int fl = *iflag;
  int d = eread(eidx, (long long)E + e, fl);
  atomicAdd(&deg[d], 1);
}

// ---- dinv = rsqrt(deg + 1) ----
__global__ __launch_bounds__(256) void k_dinv(const int* __restrict__ deg,
                                              float* __restrict__ dinv, int n) {
  int i = blockIdx.x * 256 + threadIdx.x;
  if (i < n) dinv[i] = rsqrtf((float)(deg[i] + 1));
}

// ---- exclusive scan of deg -> off and cur (single block) ----
__global__ void k_scan(const int* __restrict__ deg, int* __restrict__ off,
                       int* __restrict__ cur, int n, int E) {
  __shared__ int sums[256];
  int t = threadIdx.x;
  int chunk = (n + 255) / 256;
  int lo = t * chunk, hi = lo + chunk < n ? lo + chunk : n;
  int s = 0;
  for (int i = lo; i < hi; ++i) s += deg[i];
  sums[t] = s;
  __syncthreads();
  if (t == 0) {
    int run = 0;
    for (int i = 0; i < 256; ++i) { int v = sums[i]; sums[i] = run; run += v; }
  }
  __syncthreads();
  int run = sums[t];
  for (int i = lo; i < hi; ++i) { off[i] = run; cur[i] = run; run += deg[i]; }
  if (t == 0) off[n] = E;
}

// ---- counting-sort edges by dst: sed[slot] = (src, dinv[src]) ----
__global__ __launch_bounds__(256) void k_sort(const int* __restrict__ eidx, int E,
                                              const int* __restrict__ iflag,
                                              const float* __restrict__ dinv,
                                              int* __restrict__ cur,
                                              int2* __restrict__ sed) {
  int e = blockIdx.x * 256 + threadIdx.x;
  if (e >= E) return;
  int fl = *iflag;
  int s = eread(eidx, e, fl);
  int d = eread(eidx, (long long)E + e, fl);
  int pos = atomicAdd(&cur[d], 1);
  sed[pos] = make_int2(s, __float_as_int(dinv[s]));
}

// ---- aggregate: one wave per dst row, edge loop unrolled x4, bf16-pack to agg ----
// agg[g*64 + lane] = packbf of di*(di*x[g] + sum dinv[s]*x[s]) feature pair.
__global__ __launch_bounds__(256) void k_agg(const float* __restrict__ x,
                                             const int2* __restrict__ sed,
                                             const int* __restrict__ off,
                                             const float* __restrict__ dinv,
                                             unsigned* __restrict__ agg, int n) {
  int wid = blockIdx.x * 4 + (threadIdx.x >> 6);
  int lane = threadIdx.x & 63;
  if (wid >= n) return;
  float di = dinv[wid];
  float2 xv = *(const float2*)(x + (size_t)wid * DIM + lane * 2);
  float ax = xv.x * di, ay = xv.y * di;   // di*x[d]; final multiply by di at end
  int e0 = off[wid], e1 = off[wid + 1];
  int e = e0;
  for (; e + 4 <= e1; e += 4) {
    int2 p0 = sed[e], p1 = sed[e + 1], p2 = sed[e + 2], p3 = sed[e + 3];
    float2 v0 = *(const float2*)(x + (size_t)p0.x * DIM + lane * 2);
    float2 v1 = *(const float2*)(x + (size_t)p1.x * DIM + lane * 2);
    float2 v2 = *(const float2*)(x + (size_t)p2.x * DIM + lane * 2);
    float2 v3 = *(const float2*)(x + (size_t)p3.x * DIM + lane * 2);
    float w0 = __int_as_float(p0.y), w1 = __int_as_float(p1.y);
    float w2 = __int_as_float(p2.y), w3 = __int_as_float(p3.y);
    ax = fmaf(w0, v0.x, ax); ay = fmaf(w0, v0.y, ay);
    ax = fmaf(w1, v1.x, ax); ay = fmaf(w1, v1.y, ay);
    ax = fmaf(w2, v2.x, ax); ay = fmaf(w2, v2.y, ay);
    ax = fmaf(w3, v3.x, ax); ay = fmaf(w3, v3.y, ay);
  }
  for (; e < e1; ++e) {
    int2 p = sed[e];
    float2 v = *(const float2*)(x + (size_t)p.x * DIM + lane * 2);
    float w = __int_as_float(p.y);
    ax = fmaf(w, v.x, ax); ay = fmaf(w, v.y, ay);
  }
  agg[(size_t)wid * 64 + lane] = packbf(ax * di, ay * di);
}

// ---- GEMM: preb = bf16(agg @ W + b) + BN partials ----
// block = 256 thr, 64 rows. LDS: As2 64x68 (17KB) + Wb2 128x64 (32KB).
__global__ __launch_bounds__(256) void k_gemm(
    const unsigned* __restrict__ agg, const float* __restrict__ W,
    const float* __restrict__ bias, unsigned* __restrict__ preb,
    float* __restrict__ bnsum, float* __restrict__ bnsq, int n) {
  __shared__ unsigned As2[64 * 68];    // row-major k-pairs, stride 68
  __shared__ unsigned Wb2[DIM * 64];   // Wb2[k*64 + c2]
  int tid = threadIdx.x;
  int base = blockIdx.x * 64;

#pragma unroll
  for (int it = 0; it < 32; ++it) {
    int j = it * 256 + tid;            // j = k*64 + c2
    float2 v = ((const float2*)W)[j];
    Wb2[j] = packbf(v.x, v.y);
  }
#pragma unroll
  for (int it = 0; it < 16; ++it) {
    int idx = it * 256 + tid;          // idx = rl*64 + c2
    int rl = idx >> 6, c2 = idx & 63;
    int g = base + rl; if (g >= n) g = n - 1;
    As2[rl * 68 + c2] = agg[(size_t)g * 64 + c2];
  }
  __syncthreads();

  int cg = tid & 15, rg = tid >> 4;
  float acc[4][8];
#pragma unroll
  for (int r = 0; r < 4; ++r)
#pragma unroll
    for (int u = 0; u < 8; ++u) acc[r][u] = 0.f;

  for (int kt = 0; kt < 32; ++kt) {
    uint2 aq[4];
#pragma unroll
    for (int r = 0; r < 4; ++r)
      aq[r] = *(const uint2*)&As2[(rg * 4 + r) * 68 + kt * 2];
    float af[4][4];
#pragma unroll
    for (int r = 0; r < 4; ++r) {
      af[r][0] = bfu_lo(aq[r].x); af[r][1] = bfu_hi(aq[r].x);
      af[r][2] = bfu_lo(aq[r].y); af[r][3] = bfu_hi(aq[r].y);
    }
#pragma unroll
    for (int j = 0; j < 4; ++j) {
      int k = kt * 4 + j;
      uint4 wq = *(const uint4*)&Wb2[k * 64 + cg * 4];
      float wf[8] = {bfu_lo(wq.x), bfu_hi(wq.x), bfu_lo(wq.y), bfu_hi(wq.y),
                     bfu_lo(wq.z), bfu_hi(wq.z), bfu_lo(wq.w), bfu_hi(wq.w)};
#pragma unroll
      for (int r = 0; r < 4; ++r)
#pragma unroll
        for (int u = 0; u < 8; ++u)
          acc[r][u] = fmaf(af[r][j], wf[u], acc[r][u]);
    }
  }

  float bs[8];
#pragma unroll
  for (int u = 0; u < 8; ++u) bs[u] = bias[cg * 8 + u];
  float cs[8], cq[8];
#pragma unroll
  for (int u = 0; u < 8; ++u) { cs[u] = 0.f; cq[u] = 0.f; }

#pragma unroll
  for (int r = 0; r < 4; ++r) {
    int g = base + rg * 4 + r;
    if (g < n) {
      float v[8];
#pragma unroll
      for (int u = 0; u < 8; ++u) {
        v[u] = acc[r][u] + bs[u];
        cs[u] += v[u];
        cq[u] += v[u] * v[u];
      }
      unsigned* op = preb + (size_t)g * 64 + cg * 4;
#pragma unroll
      for (int w = 0; w < 4; ++w) op[w] = packbf(v[2 * w], v[2 * w + 1]);
    }
  }

#pragma unroll
  for (int u = 0; u < 8; ++u) {
    cs[u] += __shfl_xor(cs[u], 16); cs[u] += __shfl_xor(cs[u], 32);
    cq[u] += __shfl_xor(cq[u], 16); cq[u] += __shfl_xor(cq[u], 32);
  }
  if ((tid & 63) < 16) {
#pragma unroll
    for (int u = 0; u < 8; ++u) {
      unsafeAtomicAdd(&bnsum[cg * 8 + u], cs[u]);
      unsafeAtomicAdd(&bnsq[cg * 8 + u],  cq[u]);
    }
  }
}

// ---- BN finalize ----
__global__ void k_bn(const float* __restrict__ bnsum, const float* __restrict__ bnsq,
                     const float* __restrict__ gma, const float* __restrict__ bta,
                     float* __restrict__ sc, float* __restrict__ sh, float invn) {
  int c = threadIdx.x;
  float mean = bnsum[c] * invn;
  float var = bnsq[c] * invn - mean * mean;
  float inv = rsqrtf(var + 1e-5f);
  float g = gma[c] * inv;
  sc[c] = g;
  sh[c] = bta[c] - mean * g;
}

// ---- affine + PReLU + residual -> FP32 output ----
__global__ __launch_bounds__(256) void k_final(const unsigned* __restrict__ preb,
                                               const float* __restrict__ x,
                                               const float* __restrict__ sc,
                                               const float* __restrict__ sh,
                                               const float* __restrict__ apre,
                                               float* __restrict__ out, int n) {
  int t = blockIdx.x * 256 + threadIdx.x;
  int i = t >> 6, p = t & 63;
  if (i >= n) return;
  float a = apre[0];
  int c = p * 2;
  unsigned pk = preb[(size_t)i * 64 + p];
  float t0 = bfu_lo(pk) * sc[c] + sh[c];
  float t1 = bfu_hi(pk) * sc[c + 1] + sh[c + 1];
  t0 = t0 > 0.f ? t0 : a * t0;
  t1 = t1 > 0.f ? t1 : a * t1;
  float2 xv = *(const float2*)(x + (size_t)i * DIM + c);
  t0 += xv.x;
  t1 += xv.y;
  *(float2*)(out + (size_t)i * DIM + c) = make_float2(t0, t1);
}

extern "C" void kernel_launch(void* const* d_in, const int* in_sizes, int n_in,
                              void* d_out, int out_size, void* d_ws, size_t ws_size,
                              hipStream_t stream) {
  (void)n_in; (void)out_size; (void)ws_size;
  const float* x    = (const float*)d_in[0];
  const float* W    = (const float*)d_in[1];
  const float* b    = (const float*)d_in[2];
  const float* gma  = (const float*)d_in[3];
  const float* bta  = (const float*)d_in[4];
  const float* apre = (const float*)d_in[5];
  const int* eidx   = (const int*)d_in[6];
  float* out        = (float*)d_out;

  const int N = in_sizes[0] / DIM;
  const int E = in_sizes[6] / 2;

  char* wsb = (char*)d_ws;
  size_t off_b = 0;
  auto take = [&](size_t bytes) -> void* {
    void* p = wsb + off_b;
    off_b += (bytes + 255) & ~(size_t)255;
    return p;
  };
  int*      iflag = (int*)     take(256);
  int*      deg   = (int*)     take((size_t)N * 4);
  int*      offs  = (int*)     take((size_t)(N + 1) * 4);
  int*      cur   = (int*)     take((size_t)N * 4);
  float*    dinv  = (float*)   take((size_t)N * 4);
  int2*     sed   = (int2*)    take((size_t)E * 8);        // (src, dinv[src])
  unsigned* agg   = (unsigned*)take((size_t)N * 64 * 4);   // aggregated, bf16 pairs
  unsigned* preb  = (unsigned*)take((size_t)N * 64 * 4);   // pre-BN, bf16 pairs
  float*    bnsum = (float*)   take(DIM * 4);
  float*    bnsq  = (float*)   take(DIM * 4);
  float*    sc    = (float*)   take(DIM * 4);
  float*    sh    = (float*)   take(DIM * 4);
  // total ~65 MB

  hipMemsetAsync(deg, 0, (size_t)N * 4, stream);
  hipMemsetAsync(bnsum, 0, DIM * 4, stream);
  hipMemsetAsync(bnsq, 0, DIM * 4, stream);

  k_probe <<<1, 64, 0, stream>>>(eidx, iflag);
  k_deg   <<<(E + 255) / 256, 256, 0, stream>>>(eidx, E, iflag, deg);
  k_dinv  <<<(N + 255) / 256, 256, 0, stream>>>(deg, dinv, N);
  k_scan  <<<1, 256, 0, stream>>>(deg, offs, cur, N, E);
  k_sort  <<<(E + 255) / 256, 256, 0, stream>>>(eidx, E, iflag, dinv, cur, sed);
  k_agg   <<<(N + 3) / 4, 256, 0, stream>>>(x, sed, offs, dinv, agg, N);
  k_gemm  <<<(N + 63) / 64, 256, 0, stream>>>(agg, W, b, preb, bnsum, bnsq, N);
  k_bn    <<<1, DIM, 0, stream>>>(bnsum, bnsq, gma, bta, sc, sh, 1.0f / (float)N);
  k_final <<<(N * 64 + 255) / 256, 256, 0, stream>>>(preb, x, sc, sh, apre, out, N);
}

// Round 7
// 643.429 us; speedup vs baseline: 2.9948x; 2.9012x over previous
//
#include <hip/hip_runtime.h>

#define DIM 128

// f32 -> bf16 bits (RNE) and unpack helpers
static __device__ __forceinline__ unsigned f2bf_bits(float f) {
  unsigned u = __float_as_uint(f);
  return (u + 0x7fffu + ((u >> 16) & 1u)) >> 16;
}
static __device__ __forceinline__ unsigned packbf(float a, float b) {
  return (f2bf_bits(a) & 0xffffu) | (f2bf_bits(b) << 16);
}
static __device__ __forceinline__ float bfu_lo(unsigned pk) { return __uint_as_float(pk << 16); }
static __device__ __forceinline__ float bfu_hi(unsigned pk) { return __uint_as_float(pk & 0xffff0000u); }

// adaptive edge-index element read: fl64 ? int64 storage (lo word) : int32
static __device__ __forceinline__ int eread(const int* __restrict__ e, long long idx, int fl64) {
  return fl64 ? e[idx * 2] : e[idx];
}

// ---- probe index dtype: int64 => odd 32-bit words are all zero ----
__global__ void k_probe(const int* __restrict__ eidx, int* __restrict__ iflag) {
  int lane = threadIdx.x;  // 64
  int w = eidx[lane * 2 + 1];
  unsigned long long m = __ballot(w == 0);
  if (lane == 0) *iflag = (__popcll(m) >= 48) ? 1 : 0;
}

// ---- degree histogram over dst ----
__global__ __launch_bounds__(256) void k_deg(const int* __restrict__ eidx, int E,
                                             const int* __restrict__ iflag,
                                             int* __restrict__ deg) {
  int e = blockIdx.x * 256 + threadIdx.x;
  if (e >= E) return;
  int fl = *iflag;
  int d = eread(eidx, (long long)E + e, fl);
  atomicAdd(&deg[d], 1);
}

// ---- dinv = rsqrt(deg + 1) ----
__global__ __launch_bounds__(256) void k_dinv(const int* __restrict__ deg,
                                              float* __restrict__ dinv, int n) {
  int i = blockIdx.x * 256 + threadIdx.x;
  if (i < n) dinv[i] = rsqrtf((float)(deg[i] + 1));
}

// ---- pack x to bf16 pairs (halves gather bytes; improves L2/L3 residency) ----
__global__ __launch_bounds__(256) void k_pack(const float* __restrict__ x,
                                              unsigned* __restrict__ xb, int n) {
  int t = blockIdx.x * 256 + threadIdx.x;
  int i = t >> 6, p = t & 63;
  if (i >= n) return;
  float2 v = *(const float2*)(x + (size_t)i * DIM + p * 2);
  xb[(size_t)i * 64 + p] = packbf(v.x, v.y);
}

// ---- exclusive scan of deg -> off and cur (single block) ----
__global__ void k_scan(const int* __restrict__ deg, int* __restrict__ off,
                       int* __restrict__ cur, int n, int E) {
  __shared__ int sums[256];
  int t = threadIdx.x;
  int chunk = (n + 255) / 256;
  int lo = t * chunk, hi = lo + chunk < n ? lo + chunk : n;
  int s = 0;
  for (int i = lo; i < hi; ++i) s += deg[i];
  sums[t] = s;
  __syncthreads();
  if (t == 0) {
    int run = 0;
    for (int i = 0; i < 256; ++i) { int v = sums[i]; sums[i] = run; run += v; }
  }
  __syncthreads();
  int run = sums[t];
  for (int i = lo; i < hi; ++i) { off[i] = run; cur[i] = run; run += deg[i]; }
  if (t == 0) off[n] = E;
}

// ---- counting-sort edges by dst: sed[slot] = (src, dinv[src]) ----
__global__ __launch_bounds__(256) void k_sort(const int* __restrict__ eidx, int E,
                                              const int* __restrict__ iflag,
                                              const float* __restrict__ dinv,
                                              int* __restrict__ cur,
                                              int2* __restrict__ sed) {
  int e = blockIdx.x * 256 + threadIdx.x;
  if (e >= E) return;
  int fl = *iflag;
  int s = eread(eidx, e, fl);
  int d = eread(eidx, (long long)E + e, fl);
  int pos = atomicAdd(&cur[d], 1);
  sed[pos] = make_int2(s, __float_as_int(dinv[s]));
}

// ---- aggregate: one wave per dst row, gathers from bf16 xb, unrolled x4 ----
// agg[g*64 + lane] = packbf of di*(di*x[g] + sum dinv[s]*x[s]) feature pair.
__global__ __launch_bounds__(256) void k_agg(const unsigned* __restrict__ xb,
                                             const int2* __restrict__ sed,
                                             const int* __restrict__ off,
                                             const float* __restrict__ dinv,
                                             unsigned* __restrict__ agg, int n) {
  int wid = blockIdx.x * 4 + (threadIdx.x >> 6);
  int lane = threadIdx.x & 63;
  if (wid >= n) return;
  float di = dinv[wid];
  unsigned xp = xb[(size_t)wid * 64 + lane];
  float ax = bfu_lo(xp) * di, ay = bfu_hi(xp) * di;  // di*x[d]; final *di at end
  int e0 = off[wid], e1 = off[wid + 1];
  int e = e0;
  for (; e + 4 <= e1; e += 4) {
    int2 p0 = sed[e], p1 = sed[e + 1], p2 = sed[e + 2], p3 = sed[e + 3];
    unsigned v0 = xb[(size_t)p0.x * 64 + lane];
    unsigned v1 = xb[(size_t)p1.x * 64 + lane];
    unsigned v2 = xb[(size_t)p2.x * 64 + lane];
    unsigned v3 = xb[(size_t)p3.x * 64 + lane];
    float w0 = __int_as_float(p0.y), w1 = __int_as_float(p1.y);
    float w2 = __int_as_float(p2.y), w3 = __int_as_float(p3.y);
    ax = fmaf(w0, bfu_lo(v0), ax); ay = fmaf(w0, bfu_hi(v0), ay);
    ax = fmaf(w1, bfu_lo(v1), ax); ay = fmaf(w1, bfu_hi(v1), ay);
    ax = fmaf(w2, bfu_lo(v2), ax); ay = fmaf(w2, bfu_hi(v2), ay);
    ax = fmaf(w3, bfu_lo(v3), ax); ay = fmaf(w3, bfu_hi(v3), ay);
  }
  for (; e < e1; ++e) {
    int2 p = sed[e];
    unsigned v = xb[(size_t)p.x * 64 + lane];
    float w = __int_as_float(p.y);
    ax = fmaf(w, bfu_lo(v), ax); ay = fmaf(w, bfu_hi(v), ay);
  }
  agg[(size_t)wid * 64 + lane] = packbf(ax * di, ay * di);
}

// ---- GEMM: preb = bf16(agg @ W + b); BN partials -> part[] (NO contended atomics) ----
// block = 256 thr, 64 rows. LDS: As2 64x68 (17KB) + Wb2 128x64 (32KB).
__global__ __launch_bounds__(256) void k_gemm(
    const unsigned* __restrict__ agg, const float* __restrict__ W,
    const float* __restrict__ bias, unsigned* __restrict__ preb,
    float* __restrict__ part, int n) {
  __shared__ unsigned As2[64 * 68];    // row-major k-pairs, stride 68
  __shared__ unsigned Wb2[DIM * 64];   // Wb2[k*64 + c2]
  int tid = threadIdx.x;
  int base = blockIdx.x * 64;

#pragma unroll
  for (int it = 0; it < 32; ++it) {
    int j = it * 256 + tid;            // j = k*64 + c2
    float2 v = ((const float2*)W)[j];
    Wb2[j] = packbf(v.x, v.y);
  }
#pragma unroll
  for (int it = 0; it < 16; ++it) {
    int idx = it * 256 + tid;          // idx = rl*64 + c2
    int rl = idx >> 6, c2 = idx & 63;
    int g = base + rl; if (g >= n) g = n - 1;
    As2[rl * 68 + c2] = agg[(size_t)g * 64 + c2];
  }
  __syncthreads();

  int cg = tid & 15, rg = tid >> 4;
  int lane = tid & 63, wv = tid >> 6;
  float acc[4][8];
#pragma unroll
  for (int r = 0; r < 4; ++r)
#pragma unroll
    for (int u = 0; u < 8; ++u) acc[r][u] = 0.f;

  for (int kt = 0; kt < 32; ++kt) {
    uint2 aq[4];
#pragma unroll
    for (int r = 0; r < 4; ++r)
      aq[r] = *(const uint2*)&As2[(rg * 4 + r) * 68 + kt * 2];
    float af[4][4];
#pragma unroll
    for (int r = 0; r < 4; ++r) {
      af[r][0] = bfu_lo(aq[r].x); af[r][1] = bfu_hi(aq[r].x);
      af[r][2] = bfu_lo(aq[r].y); af[r][3] = bfu_hi(aq[r].y);
    }
#pragma unroll
    for (int j = 0; j < 4; ++j) {
      int k = kt * 4 + j;
      uint4 wq = *(const uint4*)&Wb2[k * 64 + cg * 4];
      float wf[8] = {bfu_lo(wq.x), bfu_hi(wq.x), bfu_lo(wq.y), bfu_hi(wq.y),
                     bfu_lo(wq.z), bfu_hi(wq.z), bfu_lo(wq.w), bfu_hi(wq.w)};
#pragma unroll
      for (int r = 0; r < 4; ++r)
#pragma unroll
        for (int u = 0; u < 8; ++u)
          acc[r][u] = fmaf(af[r][j], wf[u], acc[r][u]);
    }
  }

  float bs[8];
#pragma unroll
  for (int u = 0; u < 8; ++u) bs[u] = bias[cg * 8 + u];
  float cs[8], cq[8];
#pragma unroll
  for (int u = 0; u < 8; ++u) { cs[u] = 0.f; cq[u] = 0.f; }

#pragma unroll
  for (int r = 0; r < 4; ++r) {
    int g = base + rg * 4 + r;
    if (g < n) {
      float v[8];
#pragma unroll
      for (int u = 0; u < 8; ++u) {
        v[u] = acc[r][u] + bs[u];
        cs[u] += v[u];
        cq[u] += v[u] * v[u];
      }
      unsigned* op = preb + (size_t)g * 64 + cg * 4;
#pragma unroll
      for (int w = 0; w < 4; ++w) op[w] = packbf(v[2 * w], v[2 * w + 1]);
    }
  }

  // wave reduce: lanes 0..15 hold wave-total for cols cg*8..+7
#pragma unroll
  for (int u = 0; u < 8; ++u) {
    cs[u] += __shfl_xor(cs[u], 16); cs[u] += __shfl_xor(cs[u], 32);
    cq[u] += __shfl_xor(cq[u], 16); cq[u] += __shfl_xor(cq[u], 32);
  }
  __syncthreads();                    // all waves done reading As2
  float* ps = (float*)As2;            // reuse LDS: 4 waves x 256 floats
  if (lane < 16) {
#pragma unroll
    for (int u = 0; u < 8; ++u) {
      ps[wv * 256 + cg * 8 + u]       = cs[u];
      ps[wv * 256 + 128 + cg * 8 + u] = cq[u];
    }
  }
  __syncthreads();
  // tid 0..127 -> sum col tid ; tid 128..255 -> sumsq col tid-128
  float v = ps[tid] + ps[256 + tid] + ps[512 + tid] + ps[768 + tid];
  part[(size_t)blockIdx.x * 256 + tid] = v;
}

// ---- reduce per-block partials: block c of 256 -> bnsum/bnsq ----
__global__ __launch_bounds__(256) void k_red(const float* __restrict__ part, int nb,
                                             float* __restrict__ bnsum,
                                             float* __restrict__ bnsq) {
  __shared__ float red[256];
  int c = blockIdx.x, t = threadIdx.x;
  float s = 0.f;
  for (int i = t; i < nb; i += 256) s += part[(size_t)i * 256 + c];
  red[t] = s;
  __syncthreads();
  for (int k = 128; k > 0; k >>= 1) {
    if (t < k) red[t] += red[t + k];
    __syncthreads();
  }
  if (t == 0) {
    if (c < 128) bnsum[c] = red[0];
    else         bnsq[c - 128] = red[0];
  }
}

// ---- BN finalize ----
__global__ void k_bn(const float* __restrict__ bnsum, const float* __restrict__ bnsq,
                     const float* __restrict__ gma, const float* __restrict__ bta,
                     float* __restrict__ sc, float* __restrict__ sh, float invn) {
  int c = threadIdx.x;
  float mean = bnsum[c] * invn;
  float var = bnsq[c] * invn - mean * mean;
  float inv = rsqrtf(var + 1e-5f);
  float g = gma[c] * inv;
  sc[c] = g;
  sh[c] = bta[c] - mean * g;
}

// ---- affine + PReLU + residual -> FP32 output ----
__global__ __launch_bounds__(256) void k_final(const unsigned* __restrict__ preb,
                                               const float* __restrict__ x,
                                               const float* __restrict__ sc,
                                               const float* __restrict__ sh,
                                               const float* __restrict__ apre,
                                               float* __restrict__ out, int n) {
  int t = blockIdx.x * 256 + threadIdx.x;
  int i = t >> 6, p = t & 63;
  if (i >= n) return;
  float a = apre[0];
  int c = p * 2;
  unsigned pk = preb[(size_t)i * 64 + p];
  float t0 = bfu_lo(pk) * sc[c] + sh[c];
  float t1 = bfu_hi(pk) * sc[c + 1] + sh[c + 1];
  t0 = t0 > 0.f ? t0 : a * t0;
  t1 = t1 > 0.f ? t1 : a * t1;
  float2 xv = *(const float2*)(x + (size_t)i * DIM + c);
  t0 += xv.x;
  t1 += xv.y;
  *(float2*)(out + (size_t)i * DIM + c) = make_float2(t0, t1);
}

extern "C" void kernel_launch(void* const* d_in, const int* in_sizes, int n_in,
                              void* d_out, int out_size, void* d_ws, size_t ws_size,
                              hipStream_t stream) {
  (void)n_in; (void)out_size; (void)ws_size;
  const float* x    = (const float*)d_in[0];
  const float* W    = (const float*)d_in[1];
  const float* b    = (const float*)d_in[2];
  const float* gma  = (const float*)d_in[3];
  const float* bta  = (const float*)d_in[4];
  const float* apre = (const float*)d_in[5];
  const int* eidx   = (const int*)d_in[6];
  float* out        = (float*)d_out;

  const int N = in_sizes[0] / DIM;
  const int E = in_sizes[6] / 2;
  const int NB = (N + 63) / 64;   // gemm blocks

  char* wsb = (char*)d_ws;
  size_t off_b = 0;
  auto take = [&](size_t bytes) -> void* {
    void* p = wsb + off_b;
    off_b += (bytes + 255) & ~(size_t)255;
    return p;
  };
  int*      iflag = (int*)     take(256);
  int*      deg   = (int*)     take((size_t)N * 4);
  int*      offs  = (int*)     take((size_t)(N + 1) * 4);
  int*      cur   = (int*)     take((size_t)N * 4);
  float*    dinv  = (float*)   take((size_t)N * 4);
  int2*     sed   = (int2*)    take((size_t)E * 8);        // (src, dinv[src])
  unsigned* xb    = (unsigned*)take((size_t)N * 64 * 4);   // x as bf16 pairs
  unsigned* agg   = (unsigned*)take((size_t)N * 64 * 4);   // aggregated, bf16 pairs
  float*    part  = (float*)   take((size_t)NB * 256 * 4); // per-block BN partials
  float*    bnsum = (float*)   take(DIM * 4);
  float*    bnsq  = (float*)   take(DIM * 4);
  float*    sc    = (float*)   take(DIM * 4);
  float*    sh    = (float*)   take(DIM * 4);
  unsigned* preb  = agg;  // in-place: each gemm block reads only its own rows first
  // total ~68 MB

  hipMemsetAsync(deg, 0, (size_t)N * 4, stream);

  k_probe <<<1, 64, 0, stream>>>(eidx, iflag);
  k_deg   <<<(E + 255) / 256, 256, 0, stream>>>(eidx, E, iflag, deg);
  k_dinv  <<<(N + 255) / 256, 256, 0, stream>>>(deg, dinv, N);
  k_pack  <<<(N * 64 + 255) / 256, 256, 0, stream>>>(x, xb, N);
  k_scan  <<<1, 256, 0, stream>>>(deg, offs, cur, N, E);
  k_sort  <<<(E + 255) / 256, 256, 0, stream>>>(eidx, E, iflag, dinv, cur, sed);
  k_agg   <<<(N + 3) / 4, 256, 0, stream>>>(xb, sed, offs, dinv, agg, N);
  k_gemm  <<<NB, 256, 0, stream>>>(agg, W, b, preb, part, N);
  k_red   <<<256, 256, 0, stream>>>(part, NB, bnsum, bnsq);
  k_bn    <<<1, DIM, 0, stream>>>(bnsum, bnsq, gma, bta, sc, sh, 1.0f / (float)N);
  k_final <<<(N * 64 + 255) / 256, 256, 0, stream>>>(preb, x, sc, sh, apre, out, N);
}

// Round 8
// 427.540 us; speedup vs baseline: 4.5070x; 1.5050x over previous
//
#include <hip/hip_runtime.h>

#define DIM 128

// f32 -> bf16 bits (RNE) and unpack helpers
static __device__ __forceinline__ unsigned f2bf_bits(float f) {
  unsigned u = __float_as_uint(f);
  return (u + 0x7fffu + ((u >> 16) & 1u)) >> 16;
}
static __device__ __forceinline__ unsigned packbf(float a, float b) {
  return (f2bf_bits(a) & 0xffffu) | (f2bf_bits(b) << 16);
}
static __device__ __forceinline__ float bfu_lo(unsigned pk) { return __uint_as_float(pk << 16); }
static __device__ __forceinline__ float bfu_hi(unsigned pk) { return __uint_as_float(pk & 0xffff0000u); }

// adaptive edge-index element read: fl64 ? int64 storage (lo word) : int32
static __device__ __forceinline__ int eread(const int* __restrict__ e, long long idx, int fl64) {
  return fl64 ? e[idx * 2] : e[idx];
}

// ---- probe index dtype: int64 => odd 32-bit words are all zero ----
__global__ void k_probe(const int* __restrict__ eidx, int* __restrict__ iflag) {
  int lane = threadIdx.x;  // 64
  int w = eidx[lane * 2 + 1];
  unsigned long long m = __ballot(w == 0);
  if (lane == 0) *iflag = (__popcll(m) >= 48) ? 1 : 0;
}

// ---- degree histogram over dst ----
__global__ __launch_bounds__(256) void k_deg(const int* __restrict__ eidx, int E,
                                             const int* __restrict__ iflag,
                                             int* __restrict__ deg) {
  int e = blockIdx.x * 256 + threadIdx.x;
  if (e >= E) return;
  int fl = *iflag;
  int d = eread(eidx, (long long)E + e, fl);
  atomicAdd(&deg[d], 1);
}

// ---- dinv = rsqrt(deg + 1) ----
__global__ __launch_bounds__(256) void k_dinv(const int* __restrict__ deg,
                                              float* __restrict__ dinv, int n) {
  int i = blockIdx.x * 256 + threadIdx.x;
  if (i < n) dinv[i] = rsqrtf((float)(deg[i] + 1));
}

// ---- pack x to bf16 pairs (halves gather bytes; improves L2/L3 residency) ----
__global__ __launch_bounds__(256) void k_pack(const float* __restrict__ x,
                                              unsigned* __restrict__ xb, int n) {
  int t = blockIdx.x * 256 + threadIdx.x;
  int i = t >> 6, p = t & 63;
  if (i >= n) return;
  float2 v = *(const float2*)(x + (size_t)i * DIM + p * 2);
  xb[(size_t)i * 64 + p] = packbf(v.x, v.y);
}

// ---- hierarchical scan phase 1: per-block sum of 256 deg values ----
__global__ __launch_bounds__(256) void k_scan1(const int* __restrict__ deg, int n,
                                               int* __restrict__ bsum) {
  __shared__ int red[256];
  int t = threadIdx.x;
  int i = blockIdx.x * 256 + t;
  red[t] = (i < n) ? deg[i] : 0;
  __syncthreads();
  for (int k = 128; k > 0; k >>= 1) {
    if (t < k) red[t] += red[t + k];
    __syncthreads();
  }
  if (t == 0) bsum[blockIdx.x] = red[0];
}

// ---- phase 2: exclusive scan of block sums (single block, nbs small) ----
__global__ __launch_bounds__(256) void k_scan2(int* __restrict__ bsum, int nbs,
                                               int* __restrict__ off, int n, int E) {
  __shared__ int sums[256];
  int t = threadIdx.x;
  int chunk = (nbs + 255) / 256;
  int lo = t * chunk, hi = lo + chunk < nbs ? lo + chunk : nbs;
  int s = 0;
  for (int i = lo; i < hi; ++i) s += bsum[i];
  sums[t] = s;
  __syncthreads();
  if (t == 0) {
    int run = 0;
    for (int i = 0; i < 256; ++i) { int v = sums[i]; sums[i] = run; run += v; }
  }
  __syncthreads();
  int run = sums[t];
  for (int i = lo; i < hi; ++i) { int v = bsum[i]; bsum[i] = run; run += v; }
  if (t == 0) off[n] = E;
}

// ---- phase 3: block-local exclusive scan + base -> off, cur ----
__global__ __launch_bounds__(256) void k_scan3(const int* __restrict__ deg, int n,
                                               const int* __restrict__ bsum,
                                               int* __restrict__ off,
                                               int* __restrict__ cur) {
  __shared__ int s[256];
  int t = threadIdx.x;
  int i = blockIdx.x * 256 + t;
  int v = (i < n) ? deg[i] : 0;
  s[t] = v;
  __syncthreads();
  for (int d = 1; d < 256; d <<= 1) {
    int tmp = (t >= d) ? s[t - d] : 0;
    __syncthreads();
    s[t] += tmp;
    __syncthreads();
  }
  if (i < n) {
    int excl = bsum[blockIdx.x] + s[t] - v;
    off[i] = excl;
    cur[i] = excl;
  }
}

// ---- counting-sort edges by dst: sed[slot] = (src, dinv[src]) ----
__global__ __launch_bounds__(256) void k_sort(const int* __restrict__ eidx, int E,
                                              const int* __restrict__ iflag,
                                              const float* __restrict__ dinv,
                                              int* __restrict__ cur,
                                              int2* __restrict__ sed) {
  int e = blockIdx.x * 256 + threadIdx.x;
  if (e >= E) return;
  int fl = *iflag;
  int s = eread(eidx, e, fl);
  int d = eread(eidx, (long long)E + e, fl);
  int pos = atomicAdd(&cur[d], 1);
  sed[pos] = make_int2(s, __float_as_int(dinv[s]));
}

// ---- aggregate: one wave per dst row, gathers from bf16 xb, unrolled x4 ----
__global__ __launch_bounds__(256) void k_agg(const unsigned* __restrict__ xb,
                                             const int2* __restrict__ sed,
                                             const int* __restrict__ off,
                                             const float* __restrict__ dinv,
                                             unsigned* __restrict__ agg, int n) {
  int wid = blockIdx.x * 4 + (threadIdx.x >> 6);
  int lane = threadIdx.x & 63;
  if (wid >= n) return;
  float di = dinv[wid];
  unsigned xp = xb[(size_t)wid * 64 + lane];
  float ax = bfu_lo(xp) * di, ay = bfu_hi(xp) * di;  // di*x[d]; final *di at end
  int e0 = off[wid], e1 = off[wid + 1];
  int e = e0;
  for (; e + 4 <= e1; e += 4) {
    int2 p0 = sed[e], p1 = sed[e + 1], p2 = sed[e + 2], p3 = sed[e + 3];
    unsigned v0 = xb[(size_t)p0.x * 64 + lane];
    unsigned v1 = xb[(size_t)p1.x * 64 + lane];
    unsigned v2 = xb[(size_t)p2.x * 64 + lane];
    unsigned v3 = xb[(size_t)p3.x * 64 + lane];
    float w0 = __int_as_float(p0.y), w1 = __int_as_float(p1.y);
    float w2 = __int_as_float(p2.y), w3 = __int_as_float(p3.y);
    ax = fmaf(w0, bfu_lo(v0), ax); ay = fmaf(w0, bfu_hi(v0), ay);
    ax = fmaf(w1, bfu_lo(v1), ax); ay = fmaf(w1, bfu_hi(v1), ay);
    ax = fmaf(w2, bfu_lo(v2), ax); ay = fmaf(w2, bfu_hi(v2), ay);
    ax = fmaf(w3, bfu_lo(v3), ax); ay = fmaf(w3, bfu_hi(v3), ay);
  }
  for (; e < e1; ++e) {
    int2 p = sed[e];
    unsigned v = xb[(size_t)p.x * 64 + lane];
    float w = __int_as_float(p.y);
    ax = fmaf(w, bfu_lo(v), ax); ay = fmaf(w, bfu_hi(v), ay);
  }
  agg[(size_t)wid * 64 + lane] = packbf(ax * di, ay * di);
}

// ---- GEMM: preb = bf16(agg @ W + b); BN partials -> part[] ----
__global__ __launch_bounds__(256) void k_gemm(
    const unsigned* __restrict__ agg, const float* __restrict__ W,
    const float* __restrict__ bias, unsigned* __restrict__ preb,
    float* __restrict__ part, int n) {
  __shared__ unsigned As2[64 * 68];    // row-major k-pairs, stride 68
  __shared__ unsigned Wb2[DIM * 64];   // Wb2[k*64 + c2]
  int tid = threadIdx.x;
  int base = blockIdx.x * 64;

#pragma unroll
  for (int it = 0; it < 32; ++it) {
    int j = it * 256 + tid;            // j = k*64 + c2
    float2 v = ((const float2*)W)[j];
    Wb2[j] = packbf(v.x, v.y);
  }
#pragma unroll
  for (int it = 0; it < 16; ++it) {
    int idx = it * 256 + tid;          // idx = rl*64 + c2
    int rl = idx >> 6, c2 = idx & 63;
    int g = base + rl; if (g >= n) g = n - 1;
    As2[rl * 68 + c2] = agg[(size_t)g * 64 + c2];
  }
  __syncthreads();

  int cg = tid & 15, rg = tid >> 4;
  int lane = tid & 63, wv = tid >> 6;
  float acc[4][8];
#pragma unroll
  for (int r = 0; r < 4; ++r)
#pragma unroll
    for (int u = 0; u < 8; ++u) acc[r][u] = 0.f;

  for (int kt = 0; kt < 32; ++kt) {
    uint2 aq[4];
#pragma unroll
    for (int r = 0; r < 4; ++r)
      aq[r] = *(const uint2*)&As2[(rg * 4 + r) * 68 + kt * 2];
    float af[4][4];
#pragma unroll
    for (int r = 0; r < 4; ++r) {
      af[r][0] = bfu_lo(aq[r].x); af[r][1] = bfu_hi(aq[r].x);
      af[r][2] = bfu_lo(aq[r].y); af[r][3] = bfu_hi(aq[r].y);
    }
#pragma unroll
    for (int j = 0; j < 4; ++j) {
      int k = kt * 4 + j;
      uint4 wq = *(const uint4*)&Wb2[k * 64 + cg * 4];
      float wf[8] = {bfu_lo(wq.x), bfu_hi(wq.x), bfu_lo(wq.y), bfu_hi(wq.y),
                     bfu_lo(wq.z), bfu_hi(wq.z), bfu_lo(wq.w), bfu_hi(wq.w)};
#pragma unroll
      for (int r = 0; r < 4; ++r)
#pragma unroll
        for (int u = 0; u < 8; ++u)
          acc[r][u] = fmaf(af[r][j], wf[u], acc[r][u]);
    }
  }

  float bs[8];
#pragma unroll
  for (int u = 0; u < 8; ++u) bs[u] = bias[cg * 8 + u];
  float cs[8], cq[8];
#pragma unroll
  for (int u = 0; u < 8; ++u) { cs[u] = 0.f; cq[u] = 0.f; }

#pragma unroll
  for (int r = 0; r < 4; ++r) {
    int g = base + rg * 4 + r;
    if (g < n) {
      float v[8];
#pragma unroll
      for (int u = 0; u < 8; ++u) {
        v[u] = acc[r][u] + bs[u];
        cs[u] += v[u];
        cq[u] += v[u] * v[u];
      }
      unsigned* op = preb + (size_t)g * 64 + cg * 4;
#pragma unroll
      for (int w = 0; w < 4; ++w) op[w] = packbf(v[2 * w], v[2 * w + 1]);
    }
  }

#pragma unroll
  for (int u = 0; u < 8; ++u) {
    cs[u] += __shfl_xor(cs[u], 16); cs[u] += __shfl_xor(cs[u], 32);
    cq[u] += __shfl_xor(cq[u], 16); cq[u] += __shfl_xor(cq[u], 32);
  }
  __syncthreads();                    // all waves done reading As2
  float* ps = (float*)As2;            // reuse LDS: 4 waves x 256 floats
  if (lane < 16) {
#pragma unroll
    for (int u = 0; u < 8; ++u) {
      ps[wv * 256 + cg * 8 + u]       = cs[u];
      ps[wv * 256 + 128 + cg * 8 + u] = cq[u];
    }
  }
  __syncthreads();
  float v = ps[tid] + ps[256 + tid] + ps[512 + tid] + ps[768 + tid];
  part[(size_t)blockIdx.x * 256 + tid] = v;
}

// ---- reduce per-block partials: block c of 256 -> bnsum/bnsq ----
__global__ __launch_bounds__(256) void k_red(const float* __restrict__ part, int nb,
                                             float* __restrict__ bnsum,
                                             float* __restrict__ bnsq) {
  __shared__ float red[256];
  int c = blockIdx.x, t = threadIdx.x;
  float s = 0.f;
  for (int i = t; i < nb; i += 256) s += part[(size_t)i * 256 + c];
  red[t] = s;
  __syncthreads();
  for (int k = 128; k > 0; k >>= 1) {
    if (t < k) red[t] += red[t + k];
    __syncthreads();
  }
  if (t == 0) {
    if (c < 128) bnsum[c] = red[0];
    else         bnsq[c - 128] = red[0];
  }
}

// ---- BN finalize ----
__global__ void k_bn(const float* __restrict__ bnsum, const float* __restrict__ bnsq,
                     const float* __restrict__ gma, const float* __restrict__ bta,
                     float* __restrict__ sc, float* __restrict__ sh, float invn) {
  int c = threadIdx.x;
  float mean = bnsum[c] * invn;
  float var = bnsq[c] * invn - mean * mean;
  float inv = rsqrtf(var + 1e-5f);
  float g = gma[c] * inv;
  sc[c] = g;
  sh[c] = bta[c] - mean * g;
}

// ---- affine + PReLU + residual -> FP32 output ----
__global__ __launch_bounds__(256) void k_final(const unsigned* __restrict__ preb,
                                               const float* __restrict__ x,
                                               const float* __restrict__ sc,
                                               const float* __restrict__ sh,
                                               const float* __restrict__ apre,
                                               float* __restrict__ out, int n) {
  int t = blockIdx.x * 256 + threadIdx.x;
  int i = t >> 6, p = t & 63;
  if (i >= n) return;
  float a = apre[0];
  int c = p * 2;
  unsigned pk = preb[(size_t)i * 64 + p];
  float t0 = bfu_lo(pk) * sc[c] + sh[c];
  float t1 = bfu_hi(pk) * sc[c + 1] + sh[c + 1];
  t0 = t0 > 0.f ? t0 : a * t0;
  t1 = t1 > 0.f ? t1 : a * t1;
  float2 xv = *(const float2*)(x + (size_t)i * DIM + c);
  t0 += xv.x;
  t1 += xv.y;
  *(float2*)(out + (size_t)i * DIM + c) = make_float2(t0, t1);
}

extern "C" void kernel_launch(void* const* d_in, const int* in_sizes, int n_in,
                              void* d_out, int out_size, void* d_ws, size_t ws_size,
                              hipStream_t stream) {
  (void)n_in; (void)out_size; (void)ws_size;
  const float* x    = (const float*)d_in[0];
  const float* W    = (const float*)d_in[1];
  const float* b    = (const float*)d_in[2];
  const float* gma  = (const float*)d_in[3];
  const float* bta  = (const float*)d_in[4];
  const float* apre = (const float*)d_in[5];
  const int* eidx   = (const int*)d_in[6];
  float* out        = (float*)d_out;

  const int N = in_sizes[0] / DIM;
  const int E = in_sizes[6] / 2;
  const int NB = (N + 63) / 64;     // gemm blocks
  const int NBS = (N + 255) / 256;  // scan blocks

  char* wsb = (char*)d_ws;
  size_t off_b = 0;
  auto take = [&](size_t bytes) -> void* {
    void* p = wsb + off_b;
    off_b += (bytes + 255) & ~(size_t)255;
    return p;
  };
  int*      iflag = (int*)     take(256);
  int*      deg   = (int*)     take((size_t)N * 4);
  int*      offs  = (int*)     take((size_t)(N + 1) * 4);
  int*      cur   = (int*)     take((size_t)N * 4);
  int*      bsum  = (int*)     take((size_t)NBS * 4);
  float*    dinv  = (float*)   take((size_t)N * 4);
  int2*     sed   = (int2*)    take((size_t)E * 8);        // (src, dinv[src])
  unsigned* xb    = (unsigned*)take((size_t)N * 64 * 4);   // x as bf16 pairs
  unsigned* agg   = (unsigned*)take((size_t)N * 64 * 4);   // aggregated, bf16 pairs
  float*    part  = (float*)   take((size_t)NB * 256 * 4); // per-block BN partials
  float*    bnsum = (float*)   take(DIM * 4);
  float*    bnsq  = (float*)   take(DIM * 4);
  float*    sc    = (float*)   take(DIM * 4);
  float*    sh    = (float*)   take(DIM * 4);
  unsigned* preb  = agg;  // in-place: each gemm block reads only its own rows first
  // total ~68 MB

  hipMemsetAsync(deg, 0, (size_t)N * 4, stream);

  k_probe <<<1, 64, 0, stream>>>(eidx, iflag);
  k_deg   <<<(E + 255) / 256, 256, 0, stream>>>(eidx, E, iflag, deg);
  k_dinv  <<<(N + 255) / 256, 256, 0, stream>>>(deg, dinv, N);
  k_pack  <<<(N * 64 + 255) / 256, 256, 0, stream>>>(x, xb, N);
  k_scan1 <<<NBS, 256, 0, stream>>>(deg, N, bsum);
  k_scan2 <<<1, 256, 0, stream>>>(bsum, NBS, offs, N, E);
  k_scan3 <<<NBS, 256, 0, stream>>>(deg, N, bsum, offs, cur);
  k_sort  <<<(E + 255) / 256, 256, 0, stream>>>(eidx, E, iflag, dinv, cur, sed);
  k_agg   <<<(N + 3) / 4, 256, 0, stream>>>(xb, sed, offs, dinv, agg, N);
  k_gemm  <<<NB, 256, 0, stream>>>(agg, W, b, preb, part, N);
  k_red   <<<256, 256, 0, stream>>>(part, NB, bnsum, bnsq);
  k_bn    <<<1, DIM, 0, stream>>>(bnsum, bnsq, gma, bta, sc, sh, 1.0f / (float)N);
  k_final <<<(N * 64 + 255) / 256, 256, 0, stream>>>(preb, x, sc, sh, apre, out, N);
}